// Round 19
// baseline (371.575 us; speedup 1.0000x reference)
//
#include <hip/hip_runtime.h>
#include <math.h>

#define H_ 192
#define W_ 384
#define HW_ 73728

// ---------------------------------------------------------------------------
// K0: fold BN constants once.  prep layout (floats):
// [0..17] s1, [18..35] t1, [36..51] s2, [52..67] t2, [68..83] s3, [84..99] t3
// ---------------------------------------------------------------------------
__global__ void k_prep(
    const float* __restrict__ bn1g, const float* __restrict__ bn1b,
    const float* __restrict__ bn1m, const float* __restrict__ bn1v,
    const float* __restrict__ bn2g, const float* __restrict__ bn2b,
    const float* __restrict__ bn2m, const float* __restrict__ bn2v,
    const float* __restrict__ bn3g, const float* __restrict__ bn3b,
    const float* __restrict__ bn3m, const float* __restrict__ bn3v,
    float* __restrict__ prep)
{
    int t = threadIdx.x;
    if (t < 18) {
        float sc = bn1g[t] * rsqrtf(bn1v[t] + 1e-5f);
        prep[t] = sc; prep[18 + t] = bn1b[t] - bn1m[t] * sc;
    } else if (t >= 32 && t < 48) {
        int c = t - 32;
        float sc = bn2g[c] * rsqrtf(bn2v[c] + 1e-5f);
        prep[36 + c] = sc; prep[52 + c] = bn2b[c] - bn2m[c] * sc;
    } else if (t >= 64 && t < 80) {
        int c = t - 64;
        float sc = bn3g[c] * rsqrtf(bn3v[c] + 1e-5f);
        prep[68 + c] = sc; prep[84 + c] = bn3b[c] - bn3m[c] * sc;
    }
}

// ---------------------------------------------------------------------------
// K1: LDS-staged projections. grid (576, 2), 256 thr, 1 px/thread.
// y=0: stage x[64ch][256px] (64KB, float4 coalesced) once -> compute ALL
//      96 outputs (q16+k16+v64) per pixel from LDS broadcasts (2-way = free).
//      x read ONCE total (vs 3x).  ~120 VGPR; __launch_bounds__(256,2)
//      caps occupancy target so the allocator does NOT spill av[64] (R3 bug).
// y=1: gg: stage g in two 64-ch rounds, 16 outputs over 128-ch reduction.
// Weights via uniform s_load (SGPR operand on the FMA). Outputs ch-major.
// ---------------------------------------------------------------------------
__global__ __launch_bounds__(256, 2) void k_projs(
    const float* __restrict__ x, const float* __restrict__ g,
    const float* __restrict__ wq, const float* __restrict__ bq,
    const float* __restrict__ wk, const float* __restrict__ bk,
    const float* __restrict__ wv, const float* __restrict__ bv,
    const float* __restrict__ wg, const float* __restrict__ bg,
    float* __restrict__ x1, float* __restrict__ x2, float* __restrict__ x3,
    float* __restrict__ gg)
{
    __shared__ float lx[64 * 256];          // 64 KB
    int t = threadIdx.x;
    int b = blockIdx.x;                     // 0..575 ; 288 blocks per batch
    int n = b / 288;
    int sbase = (b - n * 288) * 256;
    int s = sbase + t;

    if (blockIdx.y == 0) {
        // ---- stage x tile: 4096 float4 slots / 256 threads = 16 iters ----
        const float* xp = x + n * (64 * HW_) + sbase;
#pragma unroll
        for (int i = 0; i < 16; i++) {
            int flat = i * 256 + t;          // 0..4095
            int c  = flat >> 6;
            int p4 = (flat & 63) * 4;
            *(float4*)&lx[c * 256 + p4] = *(const float4*)(xp + c * HW_ + p4);
        }
        __syncthreads();

        float aq[16], ak[16], av[64];
#pragma unroll
        for (int o = 0; o < 16; o++) { aq[o] = bq[o]; ak[o] = bk[o]; }
#pragma unroll
        for (int o = 0; o < 64; o++) av[o] = bv[o];

#pragma unroll 4
        for (int c = 0; c < 64; c++) {
            float xv = lx[c * 256 + t];
#pragma unroll
            for (int o = 0; o < 16; o++) {
                aq[o] = fmaf(wq[o * 64 + c], xv, aq[o]);
                ak[o] = fmaf(wk[o * 64 + c], xv, ak[o]);
            }
#pragma unroll
            for (int o = 0; o < 64; o++)
                av[o] = fmaf(wv[o * 64 + c], xv, av[o]);
        }

        float* d1 = x1 + n * (16 * HW_) + s;
        float* d2 = x2 + n * (16 * HW_) + s;
#pragma unroll
        for (int o = 0; o < 16; o++) {
            d1[o * HW_] = aq[o];
            d2[o * HW_] = ak[o];
        }
        float* d3 = x3 + n * (64 * HW_) + s;
#pragma unroll
        for (int o = 0; o < 64; o++) d3[o * HW_] = av[o];
    } else {
        // ---- gg: two 64-ch staging rounds over g ----
        float a[16];
#pragma unroll
        for (int o = 0; o < 16; o++) a[o] = bg[o];

#pragma unroll 1
        for (int h = 0; h < 2; h++) {
            __syncthreads();                 // protect LDS reuse across rounds
            const float* gp = g + n * (128 * HW_) + h * (64 * HW_) + sbase;
#pragma unroll
            for (int i = 0; i < 16; i++) {
                int flat = i * 256 + t;
                int c  = flat >> 6;
                int p4 = (flat & 63) * 4;
                *(float4*)&lx[c * 256 + p4] = *(const float4*)(gp + c * HW_ + p4);
            }
            __syncthreads();
#pragma unroll 4
            for (int c = 0; c < 64; c++) {
                float gv = lx[c * 256 + t];
#pragma unroll
                for (int o = 0; o < 16; o++)
                    a[o] = fmaf(wg[o * 128 + h * 64 + c], gv, a[o]);
            }
        }
        float* dst = gg + n * (16 * HW_) + s;
#pragma unroll
        for (int o = 0; o < 16; o++) dst[o * HW_] = a[o];
    }
}

// ---------------------------------------------------------------------------
// K2: tap-parallel weight logits, 1 px/thread, ZERO LDS, phase-batched loads.
// grid (576, 9). 32 independent loads issued before any use (phase A: x1/x2),
// then register-only MLP; phase B likewise for gg. BN from prep table.
// ---------------------------------------------------------------------------
struct WParams {
    const float *x1, *x2, *gg;
    const float *wp;
    const float *w1a, *w1b, *b1b, *w2a, *b2a;
    const float *prep;
    float *w1o, *w2o;   // [n][9][HW] raw logits
};

__global__ __launch_bounds__(256) void k_wtap_p(WParams P)
{
    const float* pr = P.prep;

    int k  = blockIdx.y;          // 0..8, uniform
    int ki = k / 3, kj = k - ki * 3;

    int p = blockIdx.x * 256 + threadIdx.x;
    int n = p / HW_, s = p - n * HW_;
    int hi = s / W_, wi = s - hi * W_;

    int hn = hi + ki - 1; hn = (hn < 0) ? -hn : ((hn >= H_) ? 2 * (H_ - 1) - hn : hn);
    int wn = wi + kj - 1; wn = (wn < 0) ? -wn : ((wn >= W_) ? 2 * (W_ - 1) - wn : wn);
    int snk = hn * W_ + wn;
    float dlh = (float)(hi - hn) * (2.0f / (H_ - 1));
    float dlw = (float)(wi - wn) * (2.0f / (W_ - 1));

    const float* x1p = P.x1 + n * (16 * HW_) + s;
    const float* x2p = P.x2 + n * (16 * HW_) + snk;
    const float* ggc = P.gg + n * (16 * HW_) + s;
    const float* ggn = P.gg + n * (16 * HW_) + snk;

    // ---- phase A: 32 independent loads ----
    float a0[16], a1[16];
#pragma unroll
    for (int c = 0; c < 16; c++) a0[c] = x1p[c * HW_];
#pragma unroll
    for (int c = 0; c < 16; c++) a1[c] = x2p[c * HW_];

    float f[16];
#pragma unroll
    for (int c = 0; c < 16; c++)
        f[c] = fmaxf(fmaf(a0[c] - a1[c], pr[c], pr[18 + c]), 0.0f);

    float h1[16];
#pragma unroll
    for (int o = 0; o < 16; o++) h1[o] = 0.0f;
#pragma unroll
    for (int c = 0; c < 16; c++) {
#pragma unroll
        for (int o = 0; o < 16; o++) h1[o] = fmaf(P.w1a[o * 18 + c], f[c], h1[o]);
    }
#pragma unroll
    for (int pc = 0; pc < 2; pc++) {
        float ff = fmaxf(fmaf(P.wp[pc * 2 + 0] * dlw + P.wp[pc * 2 + 1] * dlh,
                              pr[16 + pc], pr[34 + pc]), 0.0f);
#pragma unroll
        for (int o = 0; o < 16; o++) h1[o] = fmaf(P.w1a[o * 18 + 16 + pc], ff, h1[o]);
    }
    float l1 = P.b1b[0];
#pragma unroll
    for (int o = 0; o < 16; o++)
        l1 = fmaf(P.w1b[o], fmaxf(fmaf(h1[o], pr[36 + o], pr[52 + o]), 0.0f), l1);

    // ---- phase B: 32 independent loads ----
    float b0[16], b1v[16];
#pragma unroll
    for (int c = 0; c < 16; c++) b0[c] = ggc[c * HW_];
#pragma unroll
    for (int c = 0; c < 16; c++) b1v[c] = ggn[c * HW_];

    float l2 = P.b2a[0];
#pragma unroll
    for (int c = 0; c < 16; c++)
        l2 = fmaf(P.w2a[c], fmaxf(fmaf(b0[c] - b1v[c], pr[68 + c], pr[84 + c]), 0.0f), l2);

    P.w1o[(n * 9 + k) * HW_ + s] = l1;
    P.w2o[(n * 9 + k) * HW_ + s] = l2;
}

// ---------------------------------------------------------------------------
// K3: pixel-vectorized 9-tap aggregation + in-register softmax.
// grid (144, 8): 8-channel slabs.
// ---------------------------------------------------------------------------
__global__ __launch_bounds__(256) void k_agg4(
    const float* __restrict__ src, const float* __restrict__ wlog,
    float* __restrict__ dst)
{
    int tid = blockIdx.x * 256 + threadIdx.x;        // span id, 36864 total
    int cb  = blockIdx.y;
    int n   = tid / (HW_ / 4);
    int r   = tid - n * (HW_ / 4);
    int hi  = r / (W_ / 4);
    int w4  = (r - hi * (W_ / 4)) * 4;

    int h0 = (hi == 0) ? 1 : hi - 1;
    int h2 = (hi == H_ - 1) ? H_ - 2 : hi + 1;
    int rows0 = h0 * W_, rows1 = hi * W_, rows2 = h2 * W_;

    int offL = (w4 == 0)   ? 1   : w4 - 1;
    int offR = (w4 == 380) ? 382 : w4 + 4;

    const float* wl = wlog + n * 9 * HW_ + rows1 + w4;
    float4 wv[9];
#pragma unroll
    for (int k = 0; k < 9; k++) wv[k] = *(const float4*)(wl + k * HW_);
    float4 m = wv[0];
#pragma unroll
    for (int k = 1; k < 9; k++) {
        m.x = fmaxf(m.x, wv[k].x); m.y = fmaxf(m.y, wv[k].y);
        m.z = fmaxf(m.z, wv[k].z); m.w = fmaxf(m.w, wv[k].w);
    }
    float4 sum = make_float4(0.f, 0.f, 0.f, 0.f);
#pragma unroll
    for (int k = 0; k < 9; k++) {
        wv[k].x = __expf(wv[k].x - m.x); sum.x += wv[k].x;
        wv[k].y = __expf(wv[k].y - m.y); sum.y += wv[k].y;
        wv[k].z = __expf(wv[k].z - m.z); sum.z += wv[k].z;
        wv[k].w = __expf(wv[k].w - m.w); sum.w += wv[k].w;
    }
    float4 inv = make_float4(1.f / sum.x, 1.f / sum.y, 1.f / sum.z, 1.f / sum.w);
#pragma unroll
    for (int k = 0; k < 9; k++) {
        wv[k].x *= inv.x; wv[k].y *= inv.y; wv[k].z *= inv.z; wv[k].w *= inv.w;
    }

    const float* srcn = src + n * (64 * HW_);
    float* dstn = dst + n * (64 * HW_) + rows1 + w4;

#pragma unroll
    for (int ci = 0; ci < 8; ci++) {
        int c = cb * 8 + ci;
        const float* sp = srcn + c * HW_;
        float4 acc = make_float4(0.f, 0.f, 0.f, 0.f);
        int rr[3] = {rows0, rows1, rows2};
#pragma unroll
        for (int krow = 0; krow < 3; krow++) {
            const float* rowp = sp + rr[krow];
            float4 cv = *(const float4*)(rowp + w4);
            float  lf = rowp[offL];
            float  rt = rowp[offR];
            float4 wL = wv[krow * 3 + 0];
            float4 wC = wv[krow * 3 + 1];
            float4 wR = wv[krow * 3 + 2];
            acc.x = fmaf(wL.x, lf,   acc.x);
            acc.y = fmaf(wL.y, cv.x, acc.y);
            acc.z = fmaf(wL.z, cv.y, acc.z);
            acc.w = fmaf(wL.w, cv.z, acc.w);
            acc.x = fmaf(wC.x, cv.x, acc.x);
            acc.y = fmaf(wC.y, cv.y, acc.y);
            acc.z = fmaf(wC.z, cv.z, acc.z);
            acc.w = fmaf(wC.w, cv.w, acc.w);
            acc.x = fmaf(wR.x, cv.y, acc.x);
            acc.y = fmaf(wR.y, cv.z, acc.y);
            acc.z = fmaf(wR.z, cv.w, acc.z);
            acc.w = fmaf(wR.w, rt,   acc.w);
        }
        *(float4*)(dstn + c * HW_) = acc;
    }
}

// ---------------------------------------------------------------------------
extern "C" void kernel_launch(void* const* d_in, const int* in_sizes, int n_in,
                              void* d_out, int out_size, void* d_ws, size_t ws_size,
                              hipStream_t stream)
{
    const float* x    = (const float*)d_in[0];
    const float* g    = (const float*)d_in[1];
    const float* w_q  = (const float*)d_in[2];
    const float* b_q  = (const float*)d_in[3];
    const float* w_k  = (const float*)d_in[4];
    const float* b_k  = (const float*)d_in[5];
    const float* w_v  = (const float*)d_in[6];
    const float* b_v  = (const float*)d_in[7];
    const float* w_g  = (const float*)d_in[8];
    const float* b_g  = (const float*)d_in[9];
    const float* w_p  = (const float*)d_in[10];
    // d_in[11] = b_p (cancels in center-minus-neighbor subtraction)
    const float* bn1g = (const float*)d_in[12];
    const float* bn1b = (const float*)d_in[13];
    const float* bn1m = (const float*)d_in[14];
    const float* bn1v = (const float*)d_in[15];
    const float* w1a  = (const float*)d_in[16];
    const float* bn2g = (const float*)d_in[17];
    const float* bn2b = (const float*)d_in[18];
    const float* bn2m = (const float*)d_in[19];
    const float* bn2v = (const float*)d_in[20];
    const float* w1b  = (const float*)d_in[21];
    const float* b1b  = (const float*)d_in[22];
    const float* bn3g = (const float*)d_in[23];
    const float* bn3b = (const float*)d_in[24];
    const float* bn3m = (const float*)d_in[25];
    const float* bn3v = (const float*)d_in[26];
    const float* w2a  = (const float*)d_in[27];
    const float* b2a  = (const float*)d_in[28];

    float* ws    = (float*)d_ws;
    float* x1    = ws;                     // 2*16*HW = 2359296 f
    float* x2    = x1 + 2359296;           // 2359296 f
    float* gg    = x2 + 2359296;           // 2359296 f
    float* out1  = gg + 2359296;           // 2*64*HW = 9437184 f
    float* w1log = out1 + 9437184;         // 2*9*HW = 1327104 f
    float* w2log = w1log + 1327104;        // 1327104 f
    float* prep  = w2log + 1327104;        // 100 f  (total ~76.7 MB)
    float* x3    = (float*)d_out;          // d_out doubles as x3 scratch

    k_prep<<<1, 128, 0, stream>>>(bn1g, bn1b, bn1m, bn1v,
                                  bn2g, bn2b, bn2m, bn2v,
                                  bn3g, bn3b, bn3m, bn3v, prep);

    k_projs<<<dim3(576, 2), 256, 0, stream>>>(x, g, w_q, b_q, w_k, b_k,
                                              w_v, b_v, w_g, b_g,
                                              x1, x2, x3, gg);

    WParams P;
    P.x1 = x1; P.x2 = x2; P.gg = gg;
    P.wp = w_p;
    P.w1a = w1a; P.w1b = w1b; P.b1b = b1b; P.w2a = w2a; P.b2a = b2a;
    P.prep = prep;
    P.w1o = w1log; P.w2o = w2log;
    k_wtap_p<<<dim3(576, 9), 256, 0, stream>>>(P);

    k_agg4<<<dim3(144, 8), 256, 0, stream>>>(x3, w1log, out1);            // agg1
    k_agg4<<<dim3(144, 8), 256, 0, stream>>>(out1, w2log, (float*)d_out); // agg2
}

// Round 20
// 134.030 us; speedup vs baseline: 2.7723x; 2.7723x over previous
//
#include <hip/hip_runtime.h>
#include <math.h>

#define H_ 192
#define W_ 384
#define HW_ 73728

// ---------------------------------------------------------------------------
// K0: fold BN constants once.  prep layout (floats):
// [0..17] s1, [18..35] t1, [36..51] s2, [52..67] t2, [68..83] s3, [84..99] t3
// ---------------------------------------------------------------------------
__global__ void k_prep(
    const float* __restrict__ bn1g, const float* __restrict__ bn1b,
    const float* __restrict__ bn1m, const float* __restrict__ bn1v,
    const float* __restrict__ bn2g, const float* __restrict__ bn2b,
    const float* __restrict__ bn2m, const float* __restrict__ bn2v,
    const float* __restrict__ bn3g, const float* __restrict__ bn3b,
    const float* __restrict__ bn3m, const float* __restrict__ bn3v,
    float* __restrict__ prep)
{
    int t = threadIdx.x;
    if (t < 18) {
        float sc = bn1g[t] * rsqrtf(bn1v[t] + 1e-5f);
        prep[t] = sc; prep[18 + t] = bn1b[t] - bn1m[t] * sc;
    } else if (t >= 32 && t < 48) {
        int c = t - 32;
        float sc = bn2g[c] * rsqrtf(bn2v[c] + 1e-5f);
        prep[36 + c] = sc; prep[52 + c] = bn2b[c] - bn2m[c] * sc;
    } else if (t >= 64 && t < 80) {
        int c = t - 64;
        float sc = bn3g[c] * rsqrtf(bn3v[c] + 1e-5f);
        prep[68 + c] = sc; prep[84 + c] = bn3b[c] - bn3m[c] * sc;
    }
}

// ---------------------------------------------------------------------------
// K1: all projections, R12 shape + 1-deep software pipeline (R18, best):
// load batch c0+4 BEFORE FMA-ing batch c0. grid (288, 4), 2 px/thread.
// blockIdx.y: 0=q+k, 1=v[0:32], 2=v[32:64], 3=gg. Uniform s_load weights.
// ---------------------------------------------------------------------------
__global__ __launch_bounds__(256) void k_projall(
    const float* __restrict__ x, const float* __restrict__ g,
    const float* __restrict__ wq, const float* __restrict__ bq,
    const float* __restrict__ wk, const float* __restrict__ bk,
    const float* __restrict__ wv, const float* __restrict__ bv,
    const float* __restrict__ wg, const float* __restrict__ bg,
    float* __restrict__ x1, float* __restrict__ x2, float* __restrict__ x3,
    float* __restrict__ gg)
{
    int slab = blockIdx.y;
    int tid = blockIdx.x * 256 + threadIdx.x;   // 0..73727
    int n  = tid / (HW_ / 2);
    int s2 = (tid - n * (HW_ / 2)) * 2;

    if (slab == 0) {
        // ---- q + k (x read once for both) ----
        float2 aq[16], ak[16];
#pragma unroll
        for (int o = 0; o < 16; o++) {
            float b0 = bq[o], b1 = bk[o];
            aq[o] = make_float2(b0, b0); ak[o] = make_float2(b1, b1);
        }
        const float* xp = x + n * (64 * HW_) + s2;
        float2 cur[4];
#pragma unroll
        for (int j = 0; j < 4; j++) cur[j] = *(const float2*)(xp + j * HW_);
#pragma unroll 1
        for (int c0 = 0; c0 < 60; c0 += 4) {
            float2 nxt[4];
#pragma unroll
            for (int j = 0; j < 4; j++) nxt[j] = *(const float2*)(xp + (c0 + 4 + j) * HW_);
#pragma unroll
            for (int j = 0; j < 4; j++) {
#pragma unroll
                for (int o = 0; o < 16; o++) {
                    float w0 = wq[o * 64 + c0 + j];
                    float w1 = wk[o * 64 + c0 + j];
                    aq[o].x = fmaf(w0, cur[j].x, aq[o].x);
                    aq[o].y = fmaf(w0, cur[j].y, aq[o].y);
                    ak[o].x = fmaf(w1, cur[j].x, ak[o].x);
                    ak[o].y = fmaf(w1, cur[j].y, ak[o].y);
                }
            }
#pragma unroll
            for (int j = 0; j < 4; j++) cur[j] = nxt[j];
        }
#pragma unroll
        for (int j = 0; j < 4; j++) {
#pragma unroll
            for (int o = 0; o < 16; o++) {
                float w0 = wq[o * 64 + 60 + j];
                float w1 = wk[o * 64 + 60 + j];
                aq[o].x = fmaf(w0, cur[j].x, aq[o].x);
                aq[o].y = fmaf(w0, cur[j].y, aq[o].y);
                ak[o].x = fmaf(w1, cur[j].x, ak[o].x);
                ak[o].y = fmaf(w1, cur[j].y, ak[o].y);
            }
        }
        float* d1 = x1 + n * (16 * HW_) + s2;
        float* d2 = x2 + n * (16 * HW_) + s2;
#pragma unroll
        for (int o = 0; o < 16; o++) {
            *(float2*)(d1 + o * HW_) = aq[o];
            *(float2*)(d2 + o * HW_) = ak[o];
        }
    } else if (slab <= 2) {
        // ---- v half (32 outputs) ----
        int q = slab - 1;
        const float* wsel = wv + q * 2048;
        const float* bsel = bv + q * 32;
        float2 av[32];
#pragma unroll
        for (int o = 0; o < 32; o++) { float b = bsel[o]; av[o] = make_float2(b, b); }
        const float* xp = x + n * (64 * HW_) + s2;
        float2 cur[4];
#pragma unroll
        for (int j = 0; j < 4; j++) cur[j] = *(const float2*)(xp + j * HW_);
#pragma unroll 1
        for (int c0 = 0; c0 < 60; c0 += 4) {
            float2 nxt[4];
#pragma unroll
            for (int j = 0; j < 4; j++) nxt[j] = *(const float2*)(xp + (c0 + 4 + j) * HW_);
#pragma unroll
            for (int j = 0; j < 4; j++) {
#pragma unroll
                for (int o = 0; o < 32; o++) {
                    float w = wsel[o * 64 + c0 + j];
                    av[o].x = fmaf(w, cur[j].x, av[o].x);
                    av[o].y = fmaf(w, cur[j].y, av[o].y);
                }
            }
#pragma unroll
            for (int j = 0; j < 4; j++) cur[j] = nxt[j];
        }
#pragma unroll
        for (int j = 0; j < 4; j++) {
#pragma unroll
            for (int o = 0; o < 32; o++) {
                float w = wsel[o * 64 + 60 + j];
                av[o].x = fmaf(w, cur[j].x, av[o].x);
                av[o].y = fmaf(w, cur[j].y, av[o].y);
            }
        }
        float* dst = x3 + (n * 64 + q * 32) * HW_ + s2;
#pragma unroll
        for (int o = 0; o < 32; o++) *(float2*)(dst + o * HW_) = av[o];
    } else {
        // ---- gg: all 16 outputs, single pass over g ----
        float2 a[16];
#pragma unroll
        for (int o = 0; o < 16; o++) { float b = bg[o]; a[o] = make_float2(b, b); }
        const float* gp = g + n * (128 * HW_) + s2;
        float2 cur[8];
#pragma unroll
        for (int j = 0; j < 8; j++) cur[j] = *(const float2*)(gp + j * HW_);
#pragma unroll 1
        for (int c0 = 0; c0 < 120; c0 += 8) {
            float2 nxt[8];
#pragma unroll
            for (int j = 0; j < 8; j++) nxt[j] = *(const float2*)(gp + (c0 + 8 + j) * HW_);
#pragma unroll
            for (int j = 0; j < 8; j++) {
#pragma unroll
                for (int o = 0; o < 16; o++) {
                    float w = wg[o * 128 + c0 + j];
                    a[o].x = fmaf(w, cur[j].x, a[o].x);
                    a[o].y = fmaf(w, cur[j].y, a[o].y);
                }
            }
#pragma unroll
            for (int j = 0; j < 8; j++) cur[j] = nxt[j];
        }
#pragma unroll
        for (int j = 0; j < 8; j++) {
#pragma unroll
            for (int o = 0; o < 16; o++) {
                float w = wg[o * 128 + 120 + j];
                a[o].x = fmaf(w, cur[j].x, a[o].x);
                a[o].y = fmaf(w, cur[j].y, a[o].y);
            }
        }
        float* dst = gg + n * (16 * HW_) + s2;
#pragma unroll
        for (int o = 0; o < 16; o++) *(float2*)(dst + o * HW_) = a[o];
    }
}

// ---------------------------------------------------------------------------
// K2: tap-parallel weight logits, 1 px/thread, ZERO LDS, phase-batched loads.
// grid (576, 9). 32 independent loads issued before any use (phase A: x1/x2),
// then register-only MLP; phase B likewise for gg. BN from prep table.
// ---------------------------------------------------------------------------
struct WParams {
    const float *x1, *x2, *gg;
    const float *wp;
    const float *w1a, *w1b, *b1b, *w2a, *b2a;
    const float *prep;
    float *w1o, *w2o;   // [n][9][HW] raw logits
};

__global__ __launch_bounds__(256) void k_wtap_p(WParams P)
{
    const float* pr = P.prep;

    int k  = blockIdx.y;          // 0..8, uniform
    int ki = k / 3, kj = k - ki * 3;

    int p = blockIdx.x * 256 + threadIdx.x;
    int n = p / HW_, s = p - n * HW_;
    int hi = s / W_, wi = s - hi * W_;

    int hn = hi + ki - 1; hn = (hn < 0) ? -hn : ((hn >= H_) ? 2 * (H_ - 1) - hn : hn);
    int wn = wi + kj - 1; wn = (wn < 0) ? -wn : ((wn >= W_) ? 2 * (W_ - 1) - wn : wn);
    int snk = hn * W_ + wn;
    float dlh = (float)(hi - hn) * (2.0f / (H_ - 1));
    float dlw = (float)(wi - wn) * (2.0f / (W_ - 1));

    const float* x1p = P.x1 + n * (16 * HW_) + s;
    const float* x2p = P.x2 + n * (16 * HW_) + snk;
    const float* ggc = P.gg + n * (16 * HW_) + s;
    const float* ggn = P.gg + n * (16 * HW_) + snk;

    // ---- phase A: 32 independent loads ----
    float a0[16], a1[16];
#pragma unroll
    for (int c = 0; c < 16; c++) a0[c] = x1p[c * HW_];
#pragma unroll
    for (int c = 0; c < 16; c++) a1[c] = x2p[c * HW_];

    float f[16];
#pragma unroll
    for (int c = 0; c < 16; c++)
        f[c] = fmaxf(fmaf(a0[c] - a1[c], pr[c], pr[18 + c]), 0.0f);

    float h1[16];
#pragma unroll
    for (int o = 0; o < 16; o++) h1[o] = 0.0f;
#pragma unroll
    for (int c = 0; c < 16; c++) {
#pragma unroll
        for (int o = 0; o < 16; o++) h1[o] = fmaf(P.w1a[o * 18 + c], f[c], h1[o]);
    }
#pragma unroll
    for (int pc = 0; pc < 2; pc++) {
        float ff = fmaxf(fmaf(P.wp[pc * 2 + 0] * dlw + P.wp[pc * 2 + 1] * dlh,
                              pr[16 + pc], pr[34 + pc]), 0.0f);
#pragma unroll
        for (int o = 0; o < 16; o++) h1[o] = fmaf(P.w1a[o * 18 + 16 + pc], ff, h1[o]);
    }
    float l1 = P.b1b[0];
#pragma unroll
    for (int o = 0; o < 16; o++)
        l1 = fmaf(P.w1b[o], fmaxf(fmaf(h1[o], pr[36 + o], pr[52 + o]), 0.0f), l1);

    // ---- phase B: 32 independent loads ----
    float b0[16], b1v[16];
#pragma unroll
    for (int c = 0; c < 16; c++) b0[c] = ggc[c * HW_];
#pragma unroll
    for (int c = 0; c < 16; c++) b1v[c] = ggn[c * HW_];

    float l2 = P.b2a[0];
#pragma unroll
    for (int c = 0; c < 16; c++)
        l2 = fmaf(P.w2a[c], fmaxf(fmaf(b0[c] - b1v[c], pr[68 + c], pr[84 + c]), 0.0f), l2);

    P.w1o[(n * 9 + k) * HW_ + s] = l1;
    P.w2o[(n * 9 + k) * HW_ + s] = l2;
}

// ---------------------------------------------------------------------------
// K3: pixel-vectorized 9-tap aggregation + in-register softmax.
// grid (144, 8): 8-channel slabs.
// ---------------------------------------------------------------------------
__global__ __launch_bounds__(256) void k_agg4(
    const float* __restrict__ src, const float* __restrict__ wlog,
    float* __restrict__ dst)
{
    int tid = blockIdx.x * 256 + threadIdx.x;        // span id, 36864 total
    int cb  = blockIdx.y;
    int n   = tid / (HW_ / 4);
    int r   = tid - n * (HW_ / 4);
    int hi  = r / (W_ / 4);
    int w4  = (r - hi * (W_ / 4)) * 4;

    int h0 = (hi == 0) ? 1 : hi - 1;
    int h2 = (hi == H_ - 1) ? H_ - 2 : hi + 1;
    int rows0 = h0 * W_, rows1 = hi * W_, rows2 = h2 * W_;

    int offL = (w4 == 0)   ? 1   : w4 - 1;
    int offR = (w4 == 380) ? 382 : w4 + 4;

    const float* wl = wlog + n * 9 * HW_ + rows1 + w4;
    float4 wv[9];
#pragma unroll
    for (int k = 0; k < 9; k++) wv[k] = *(const float4*)(wl + k * HW_);
    float4 m = wv[0];
#pragma unroll
    for (int k = 1; k < 9; k++) {
        m.x = fmaxf(m.x, wv[k].x); m.y = fmaxf(m.y, wv[k].y);
        m.z = fmaxf(m.z, wv[k].z); m.w = fmaxf(m.w, wv[k].w);
    }
    float4 sum = make_float4(0.f, 0.f, 0.f, 0.f);
#pragma unroll
    for (int k = 0; k < 9; k++) {
        wv[k].x = __expf(wv[k].x - m.x); sum.x += wv[k].x;
        wv[k].y = __expf(wv[k].y - m.y); sum.y += wv[k].y;
        wv[k].z = __expf(wv[k].z - m.z); sum.z += wv[k].z;
        wv[k].w = __expf(wv[k].w - m.w); sum.w += wv[k].w;
    }
    float4 inv = make_float4(1.f / sum.x, 1.f / sum.y, 1.f / sum.z, 1.f / sum.w);
#pragma unroll
    for (int k = 0; k < 9; k++) {
        wv[k].x *= inv.x; wv[k].y *= inv.y; wv[k].z *= inv.z; wv[k].w *= inv.w;
    }

    const float* srcn = src + n * (64 * HW_);
    float* dstn = dst + n * (64 * HW_) + rows1 + w4;

#pragma unroll
    for (int ci = 0; ci < 8; ci++) {
        int c = cb * 8 + ci;
        const float* sp = srcn + c * HW_;
        float4 acc = make_float4(0.f, 0.f, 0.f, 0.f);
        int rr[3] = {rows0, rows1, rows2};
#pragma unroll
        for (int krow = 0; krow < 3; krow++) {
            const float* rowp = sp + rr[krow];
            float4 cv = *(const float4*)(rowp + w4);
            float  lf = rowp[offL];
            float  rt = rowp[offR];
            float4 wL = wv[krow * 3 + 0];
            float4 wC = wv[krow * 3 + 1];
            float4 wR = wv[krow * 3 + 2];
            acc.x = fmaf(wL.x, lf,   acc.x);
            acc.y = fmaf(wL.y, cv.x, acc.y);
            acc.z = fmaf(wL.z, cv.y, acc.z);
            acc.w = fmaf(wL.w, cv.z, acc.w);
            acc.x = fmaf(wC.x, cv.x, acc.x);
            acc.y = fmaf(wC.y, cv.y, acc.y);
            acc.z = fmaf(wC.z, cv.z, acc.z);
            acc.w = fmaf(wC.w, cv.w, acc.w);
            acc.x = fmaf(wR.x, cv.y, acc.x);
            acc.y = fmaf(wR.y, cv.z, acc.y);
            acc.z = fmaf(wR.z, cv.w, acc.z);
            acc.w = fmaf(wR.w, rt,   acc.w);
        }
        *(float4*)(dstn + c * HW_) = acc;
    }
}

// ---------------------------------------------------------------------------
extern "C" void kernel_launch(void* const* d_in, const int* in_sizes, int n_in,
                              void* d_out, int out_size, void* d_ws, size_t ws_size,
                              hipStream_t stream)
{
    const float* x    = (const float*)d_in[0];
    const float* g    = (const float*)d_in[1];
    const float* w_q  = (const float*)d_in[2];
    const float* b_q  = (const float*)d_in[3];
    const float* w_k  = (const float*)d_in[4];
    const float* b_k  = (const float*)d_in[5];
    const float* w_v  = (const float*)d_in[6];
    const float* b_v  = (const float*)d_in[7];
    const float* w_g  = (const float*)d_in[8];
    const float* b_g  = (const float*)d_in[9];
    const float* w_p  = (const float*)d_in[10];
    // d_in[11] = b_p (cancels in center-minus-neighbor subtraction)
    const float* bn1g = (const float*)d_in[12];
    const float* bn1b = (const float*)d_in[13];
    const float* bn1m = (const float*)d_in[14];
    const float* bn1v = (const float*)d_in[15];
    const float* w1a  = (const float*)d_in[16];
    const float* bn2g = (const float*)d_in[17];
    const float* bn2b = (const float*)d_in[18];
    const float* bn2m = (const float*)d_in[19];
    const float* bn2v = (const float*)d_in[20];
    const float* w1b  = (const float*)d_in[21];
    const float* b1b  = (const float*)d_in[22];
    const float* bn3g = (const float*)d_in[23];
    const float* bn3b = (const float*)d_in[24];
    const float* bn3m = (const float*)d_in[25];
    const float* bn3v = (const float*)d_in[26];
    const float* w2a  = (const float*)d_in[27];
    const float* b2a  = (const float*)d_in[28];

    float* ws    = (float*)d_ws;
    float* x1    = ws;                     // 2*16*HW = 2359296 f
    float* x2    = x1 + 2359296;           // 2359296 f
    float* gg    = x2 + 2359296;           // 2359296 f
    float* out1  = gg + 2359296;           // 2*64*HW = 9437184 f
    float* w1log = out1 + 9437184;         // 2*9*HW = 1327104 f
    float* w2log = w1log + 1327104;        // 1327104 f
    float* prep  = w2log + 1327104;        // 100 f  (total ~76.7 MB)
    float* x3    = (float*)d_out;          // d_out doubles as x3 scratch

    k_prep<<<1, 128, 0, stream>>>(bn1g, bn1b, bn1m, bn1v,
                                  bn2g, bn2b, bn2m, bn2v,
                                  bn3g, bn3b, bn3m, bn3v, prep);

    k_projall<<<dim3(288, 4), 256, 0, stream>>>(x, g, w_q, b_q, w_k, b_k,
                                                w_v, b_v, w_g, b_g,
                                                x1, x2, x3, gg);

    WParams P;
    P.x1 = x1; P.x2 = x2; P.gg = gg;
    P.wp = w_p;
    P.w1a = w1a; P.w1b = w1b; P.b1b = b1b; P.w2a = w2a; P.b2a = b2a;
    P.prep = prep;
    P.w1o = w1log; P.w2o = w2log;
    k_wtap_p<<<dim3(576, 9), 256, 0, stream>>>(P);

    k_agg4<<<dim3(144, 8), 256, 0, stream>>>(x3, w1log, out1);            // agg1
    k_agg4<<<dim3(144, 8), 256, 0, stream>>>(out1, w2log, (float*)d_out); // agg2
}